// Round 5
// baseline (357.334 us; speedup 1.0000x reference)
//
#include <hip/hip_runtime.h>
#include <stdint.h>

#define DEV __device__ __forceinline__

typedef __attribute__((ext_vector_type(8))) short bf16x8;
typedef __attribute__((ext_vector_type(4))) float f32x4;
typedef __attribute__((ext_vector_type(8))) unsigned short u16x8;
typedef __attribute__((ext_vector_type(4))) unsigned short u16x4;

DEV unsigned short f2bf(float f) {
  union { float f; unsigned int u; } v; v.f = f;
  unsigned int u = v.u;
  return (unsigned short)((u + 0x7FFFu + ((u >> 16) & 1u)) >> 16);
}
DEV float bf2f(unsigned short u) {
  union { unsigned int u; float f; } v; v.u = ((unsigned int)u) << 16;
  return v.f;
}
DEV f32x4 mfma16(bf16x8 a, bf16x8 b, f32x4 c) {
  return __builtin_amdgcn_mfma_f32_16x16x32_bf16(a, b, c, 0, 0, 0);
}
DEV void gl_lds16(const void* g, void* l) {
  __builtin_amdgcn_global_load_lds(
      (const __attribute__((address_space(1))) void*)g,
      (__attribute__((address_space(3))) void*)l, 16, 0, 0);
}

// ---------------- convert x (fp32 -> bf16) ----------------
__global__ __launch_bounds__(256) void k_cvt_bf16(const float* __restrict__ in,
                                                  unsigned short* __restrict__ out,
                                                  int n8) {
  int i = blockIdx.x * 256 + threadIdx.x;
  if (i >= n8) return;
  const float4* p = (const float4*)in + (size_t)i * 2;
  float4 a = p[0], b = p[1];
  u16x8 o;
  o[0] = f2bf(a.x); o[1] = f2bf(a.y); o[2] = f2bf(a.z); o[3] = f2bf(a.w);
  o[4] = f2bf(b.x); o[5] = f2bf(b.y); o[6] = f2bf(b.z); o[7] = f2bf(b.w);
  ((u16x8*)out)[i] = o;
}

// ---------------- GK[h][s][dd] = sum_d Wk[dd][d] * G[h,s,d] ----------------
__global__ void k_gk(const float* __restrict__ Wk, const float* __restrict__ qg,
                     float* __restrict__ GK) {
  int idx = blockIdx.x * 256 + threadIdx.x;  // 32768
  int dd = idx & 63, hs = idx >> 6;
  float a = 0.f;
#pragma unroll 8
  for (int d = 0; d < 64; ++d) a += Wk[dd * 64 + d] * qg[(size_t)hs * 64 + d];
  GK[idx] = a;
}

// ---------------- Wcat rows 0..511: Wl^T[hs][c] = sum_dd Wx[c][h*64+dd]*GK[h,s,dd] ----
__global__ void k_wl(const float* __restrict__ Wx, const float* __restrict__ GK,
                     unsigned short* __restrict__ Wcat) {
  int idx = blockIdx.x * 256 + threadIdx.x;  // 262144
  int c = idx & 511, hs = idx >> 9;
  int h = hs >> 6;
  float a = 0.f;
#pragma unroll 8
  for (int dd = 0; dd < 64; ++dd) a += Wx[(size_t)c * 512 + h * 64 + dd] * GK[hs * 64 + dd];
  Wcat[(size_t)hs * 512 + c] = f2bf(a);
}

// ---------------- Wcat rows 512..1023: Wv^T fused ----------------
__global__ void k_wv(const float* __restrict__ Wx, const float* __restrict__ Wv,
                     unsigned short* __restrict__ Wcat) {
  int idx = blockIdx.x * 256 + threadIdx.x;  // 262144
  int c = idx & 511, o = idx >> 9;
  int h = o >> 6, dp = o & 63;
  float a = 0.f;
#pragma unroll 8
  for (int dd = 0; dd < 64; ++dd) a += Wx[(size_t)c * 512 + h * 64 + dd] * Wv[dd * 64 + dp];
  Wcat[(size_t)(512 + o) * 512 + c] = f2bf(a);
}

// ---------------- fused biases via GK ----------------
__global__ void k_bias2(const float* __restrict__ bx, const float* __restrict__ bk,
                        const float* __restrict__ bv, const float* __restrict__ Wv,
                        const float* __restrict__ qg, const float* __restrict__ GK,
                        float* __restrict__ bias) {
  int o = blockIdx.x * 256 + threadIdx.x;
  if (o >= 1024) return;
  if (o < 512) {
    int h = o >> 6;
    float a = 0.f;
    for (int dd = 0; dd < 64; ++dd) a += bx[h * 64 + dd] * GK[(size_t)o * 64 + dd];
    for (int dp = 0; dp < 64; ++dp) a += bk[dp] * qg[(size_t)o * 64 + dp];
    bias[o] = a;
  } else {
    int o2 = o - 512, h = o2 >> 6, dp = o2 & 63;
    float a = bv[dp];
    for (int dd = 0; dd < 64; ++dd) a += bx[h * 64 + dd] * Wv[dd * 64 + dp];
    bias[o] = a;
  }
}

__global__ void k_wo_t(const float* __restrict__ Wo, unsigned short* __restrict__ WoT) {
  int idx = blockIdx.x * 256 + threadIdx.x;  // 262144
  int i = idx >> 9, o = idx & 511;
  WoT[(size_t)o * 512 + i] = f2bf(Wo[(size_t)i * 512 + o]);
}

// =================== 256x256 8-phase GEMM (T1+T2+T3+T4+T5) ===================
// 8 waves (2Mx4N), BK=64, K=512 (8 K-tiles, 4 iters x 2 tiles). 128 KiB LDS:
// [db][A 32KB | B 32KB], XOR-swizzled via pre-swizzled global source.
// Per phase: [vmcnt?][barrier][stage 1 half-tile][ds_read batch {12,4,8,0}]
//            [lgkmcnt(0)+sched_barrier][setprio 16-MFMA quadrant setprio].
// Stage targets: db0 halves at ph4-7, db1 halves at ph8,1,2,3 (one phase after
// that buffer's last reads drained block-wide). vmcnt(2) at ph1/ph5 only
// (all other phases' needs implied); ph5 of last iter drains vmcnt(0).
template <int MODE>
__global__ __launch_bounds__(512, 1) void k_mm(const unsigned short* __restrict__ A,
                                               const unsigned short* __restrict__ BTg,
                                               const float* __restrict__ bias,
                                               float* __restrict__ outF,
                                               unsigned short* __restrict__ P2,
                                               unsigned short* __restrict__ LTe,
                                               unsigned short* __restrict__ vT, int NT) {
  extern __shared__ char ldsb[];  // 131072
  const int tid = threadIdx.x;
  const int w = tid >> 6, lane = tid & 63, l = lane & 15, g = lane >> 4;
  unsigned bid = blockIdx.x, perx = gridDim.x >> 3;
  unsigned nbid = (bid & 7) * perx + (bid >> 3);
  const int ntile = nbid % NT, mtile = nbid / NT;
  const int bm = mtile * 256, bn = ntile * 256;
  const int wm = (w >> 2) * 128, wn = (w & 3) * 64;
  const int b = bm >> 14;
  const unsigned short* BT = (MODE == 0) ? BTg + ((size_t)b << 18) : BTg;
  const int sw = (l & 7) << 4;
  f32x4 acc[8][4] = {};
  bf16x8 afr[4][2], bfr[4][2];

#define STAGEH(db, isB, half, kt)                                              \
  {                                                                            \
    const unsigned short* sp_ = (isB) ? BT : A;                                \
    const int rb_ = (isB) ? bn : bm;                                           \
    _Pragma("unroll") for (int j_ = 0; j_ < 2; ++j_) {                         \
      int off_ = j_ * 8192 + tid * 16;                                         \
      int row_ = (half) * 128 + (off_ >> 7);                                   \
      int cb_ = (off_ & 127) ^ ((row_ & 7) << 4);                              \
      gl_lds16(sp_ + (size_t)(rb_ + row_) * 512 + (kt) * 64 + (cb_ >> 1),      \
               ldsb + (db) * 65536 + (isB) * 32768 + (half) * 16384 + off_);   \
    }                                                                          \
  }
#define RDA(db, f0)                                                            \
  _Pragma("unroll") for (int j_ = 0; j_ < 4; ++j_)                             \
      _Pragma("unroll") for (int ks_ = 0; ks_ < 2; ++ks_)                      \
          afr[j_][ks_] = *(const bf16x8*)(ldsb + (db) * 65536 +                \
              (wm + ((f0) + j_) * 16 + l) * 128 + ((ks_ * 64 + g * 16) ^ sw));
#define RDB(db, n0)                                                            \
  _Pragma("unroll") for (int j_ = 0; j_ < 2; ++j_)                             \
      _Pragma("unroll") for (int ks_ = 0; ks_ < 2; ++ks_)                      \
          bfr[(n0) + j_][ks_] = *(const bf16x8*)(ldsb + (db) * 65536 + 32768 + \
              (wn + ((n0) + j_) * 16 + l) * 128 + ((ks_ * 64 + g * 16) ^ sw));
#define QUAD(fo, no)                                                           \
  __builtin_amdgcn_s_setprio(1);                                               \
  _Pragma("unroll") for (int j_ = 0; j_ < 4; ++j_)                             \
      _Pragma("unroll") for (int n_ = 0; n_ < 2; ++n_) {                       \
    acc[(fo)+j_][(no)+n_] = mfma16(afr[j_][0], bfr[(no)+n_][0], acc[(fo)+j_][(no)+n_]); \
    acc[(fo)+j_][(no)+n_] = mfma16(afr[j_][1], bfr[(no)+n_][1], acc[(fo)+j_][(no)+n_]); \
  }                                                                            \
  __builtin_amdgcn_s_setprio(0);
#define LGKM0                                        \
  asm volatile("s_waitcnt lgkmcnt(0)" ::: "memory"); \
  __builtin_amdgcn_sched_barrier(0);
#define VMC(n) asm volatile("s_waitcnt vmcnt(" #n ")" ::: "memory");
#define BAR __builtin_amdgcn_s_barrier();

  // prologue: tile0 (db0, D4..D7 pattern) + tile1 B-lo (db1, D8 pattern)
  STAGEH(0, 1, 0, 0) STAGEH(0, 1, 1, 0) STAGEH(0, 0, 0, 0) STAGEH(0, 0, 1, 0)
  STAGEH(1, 1, 0, 1)

  for (int i = 0; i < 4; ++i) {
    const int ktB = 2 * i + 1, ktC = 2 * i + 2, ktD = 2 * i + 3;
    const bool more = (i < 3);
    // ph1: compute ktA(db0) q1; stage db1 B-hi (ktB h2)
    VMC(2) BAR
    STAGEH(1, 1, 1, ktB)
    RDA(0, 0) RDB(0, 0)
    LGKM0
    QUAD(0, 0)
    // ph2: q2; stage db1 A-lo (ktB h3)
    BAR
    STAGEH(1, 0, 0, ktB)
    RDB(0, 2)
    LGKM0
    QUAD(0, 2)
    // ph3: q3; stage db1 A-hi (ktB h4)
    BAR
    STAGEH(1, 0, 1, ktB)
    RDA(0, 4)
    LGKM0
    QUAD(4, 0)
    // ph4: q4; stage db0 B-lo (ktC h1)
    BAR
    if (more) { STAGEH(0, 1, 0, ktC) }
    QUAD(4, 2)
    // ph5: compute ktB(db1) q1; stage db0 B-hi (ktC h2)
    if (more) { VMC(2) } else { VMC(0) }
    BAR
    if (more) { STAGEH(0, 1, 1, ktC) }
    RDA(1, 0) RDB(1, 0)
    LGKM0
    QUAD(0, 0)
    // ph6: q2; stage db0 A-lo (ktC h3)
    BAR
    if (more) { STAGEH(0, 0, 0, ktC) }
    RDB(1, 2)
    LGKM0
    QUAD(0, 2)
    // ph7: q3; stage db0 A-hi (ktC h4)
    BAR
    if (more) { STAGEH(0, 0, 1, ktC) }
    RDA(1, 4)
    LGKM0
    QUAD(4, 0)
    // ph8: q4; stage db1 B-lo (ktD h1)
    BAR
    if (more) { STAGEH(1, 1, 0, ktD) }
    QUAD(4, 2)
  }
#undef STAGEH
#undef RDA
#undef RDB
#undef QUAD
#undef LGKM0
#undef VMC
#undef BAR

  if (MODE == 0) {
#pragma unroll
    for (int fm = 0; fm < 8; ++fm)
#pragma unroll
      for (int fn = 0; fn < 4; ++fn) {
        int col = bn + wn + fn * 16 + l;
        float bb2 = bias[col];
        int row0 = bm + wm + fm * 16 + g * 4;
#pragma unroll
        for (int r = 0; r < 4; ++r)
          outF[(size_t)(row0 + r) * 512 + col] = acc[fm][fn][r] + bb2;
      }
  } else if (bn < 512) {
    int hglob = (bn >> 6) + (w & 3);
    int nloc0 = (bm & 16383) + wm;
#pragma unroll
    for (int fm = 0; fm < 8; ++fm)
#pragma unroll
      for (int fn = 0; fn < 4; ++fn) {
        float bb2 = bias[bn + wn + fn * 16 + l];
#pragma unroll
        for (int r = 0; r < 4; ++r)
          acc[fm][fn][r] = __expf(acc[fm][fn][r] + bb2 - 8.0f);
      }
#pragma unroll
    for (int fm = 0; fm < 8; ++fm) {
      f32x4 rs;
#pragma unroll
      for (int r = 0; r < 4; ++r)
        rs[r] = (acc[fm][0][r] + acc[fm][1][r]) + (acc[fm][2][r] + acc[fm][3][r]);
#pragma unroll
      for (int m = 1; m < 16; m <<= 1)
#pragma unroll
        for (int r = 0; r < 4; ++r) rs[r] += __shfl_xor(rs[r], m);
      int nglob0 = bm + wm + fm * 16 + g * 4;
#pragma unroll
      for (int r = 0; r < 4; ++r) {
        float rinv = 1.f / rs[r];
#pragma unroll
        for (int fn = 0; fn < 4; ++fn)
          P2[(size_t)(nglob0 + r) * 512 + bn + wn + fn * 16 + l] =
              f2bf(acc[fm][fn][r] * rinv);
      }
#pragma unroll
      for (int fn = 0; fn < 4; ++fn) {
        int s = fn * 16 + l;
        u16x4 o;
#pragma unroll
        for (int r = 0; r < 4; ++r) o[r] = f2bf(acc[fm][fn][r]);
        *(u16x4*)&LTe[((size_t)((b * 8 + hglob) * 64 + s)) * 16384 + nloc0 + fm * 16 + g * 4] = o;
      }
    }
  } else {
    int nloc0 = (bm & 16383) + wm;
#pragma unroll
    for (int fm = 0; fm < 8; ++fm)
#pragma unroll
      for (int fn = 0; fn < 4; ++fn) {
        int c2 = bn - 512 + wn + fn * 16 + l;
        float bb2 = bias[bn + wn + fn * 16 + l];
        int h = c2 >> 6, d = c2 & 63;
        u16x4 o;
#pragma unroll
        for (int r = 0; r < 4; ++r) o[r] = f2bf(acc[fm][fn][r] + bb2);
        *(u16x4*)&vT[(((size_t)(b * 8 + h)) * 64 + d) * 16384 + nloc0 + fm * 16 + g * 4] = o;
      }
  }
}

// ---------------- pass 1: z_part = LTe @ v (pure streaming GEMM) + den ----------------
__global__ __launch_bounds__(256) void k_pass1(const unsigned short* __restrict__ LTe,
                                               const unsigned short* __restrict__ vT,
                                               float* __restrict__ zpart,
                                               float* __restrict__ dpart) {
  int chunk = blockIdx.x, bh = blockIdx.y;
  int tid = threadIdx.x, w = tid >> 6, lane = tid & 63, l = lane & 15, g = lane >> 4;
  const unsigned short* lp = LTe + ((size_t)bh * 64 + w * 16 + l) * 16384 + chunk * 512;
  const unsigned short* vp = vT + (size_t)bh * 64 * 16384 + chunk * 512;
  f32x4 acc[4] = {};
  float dsum = 0.f;
#pragma unroll 4
  for (int ks = 0; ks < 16; ++ks) {
    bf16x8 a = *(const bf16x8*)(lp + ks * 32 + g * 8);
#pragma unroll
    for (int e = 0; e < 8; ++e) dsum += bf2f((unsigned short)a[e]);
#pragma unroll
    for (int fd = 0; fd < 4; ++fd) {
      bf16x8 bv = *(const bf16x8*)(vp + ((size_t)(fd * 16 + l)) * 16384 + ks * 32 + g * 8);
      acc[fd] = mfma16(a, bv, acc[fd]);
    }
  }
  dsum += __shfl_xor(dsum, 16);
  dsum += __shfl_xor(dsum, 32);
  size_t base = ((size_t)bh * 32 + chunk) * 64;
  if (g == 0) dpart[base + w * 16 + l] = dsum;
#pragma unroll
  for (int fd = 0; fd < 4; ++fd)
#pragma unroll
    for (int r = 0; r < 4; ++r)
      zpart[(base + w * 16 + g * 4 + r) * 64 + fd * 16 + l] = acc[fd][r];
}

// ---------------- reduce partials -> z fp32 [bh][s][d] ----------------
__global__ void k_zred(const float* __restrict__ zpart, const float* __restrict__ dpart,
                       float* __restrict__ z) {
  int idx = blockIdx.x * 256 + threadIdx.x;  // 131072
  int bh = idx >> 12, s = (idx >> 6) & 63, d = idx & 63;
  float num = 0.f, den = 0.f;
  for (int c = 0; c < 32; ++c) {
    num += zpart[(((size_t)bh * 32 + c) * 64 + s) * 64 + d];
    den += dpart[((size_t)bh * 32 + c) * 64 + s];
  }
  z[idx] = num / den;
}

// ---------------- zWoT[b][c][hs] = sum_d z[b,h,s,d] * WoT[c][h*64+d] ----------------
__global__ void k_zwo(const float* __restrict__ z, const unsigned short* __restrict__ WoT,
                      unsigned short* __restrict__ zWoT) {
  int idx = blockIdx.x * 256 + threadIdx.x;  // 1048576
  int hs = idx & 511, c = (idx >> 9) & 511, b = idx >> 18;
  int h = hs >> 6;
  const float* zp = z + ((size_t)(b * 8 + h) * 64 + (hs & 63)) * 64;
  const unsigned short* wp = WoT + (size_t)c * 512 + h * 64;
  float a = 0.f;
#pragma unroll 8
  for (int d = 0; d < 64; ++d) a += zp[d] * bf2f(wp[d]);
  zWoT[((size_t)(b * 512) + c) * 512 + hs] = f2bf(a);
}

extern "C" void kernel_launch(void* const* d_in, const int* in_sizes, int n_in,
                              void* d_out, int out_size, void* d_ws, size_t ws_size,
                              hipStream_t stream) {
  const float* x  = (const float*)d_in[0];
  const float* qg = (const float*)d_in[1];
  const float* Wx = (const float*)d_in[2];
  const float* bx = (const float*)d_in[3];
  const float* Wk = (const float*)d_in[4];
  const float* bk = (const float*)d_in[5];
  const float* Wv = (const float*)d_in[6];
  const float* bv = (const float*)d_in[7];
  const float* Wo = (const float*)d_in[8];
  const float* bo = (const float*)d_in[9];
  float* out = (float*)d_out;

  char* ws = (char*)d_ws;
  unsigned short* xbf  = (unsigned short*)(ws);               // 64 MiB (dead after GEMM1)
  float* zpart         = (float*)(ws);                        // 32 MiB, reuses xbf region
  unsigned short* P2   = (unsigned short*)(ws + 67108864);    // 64 MiB
  unsigned short* Wcat = (unsigned short*)(ws + 134217728);   // 1 MiB
  unsigned short* WoT  = (unsigned short*)(ws + 135266304);   // 0.5 MiB
  float* bias          = (float*)(ws + 135790592);            // 4 KiB
  float* GK            = (float*)(ws + 135794688);            // 128 KiB
  unsigned short* zWoT = (unsigned short*)(ws + 135925760);   // 2 MiB
  float* dpart         = (float*)(ws + 138027008);            // 256 KiB
  float* zbuf          = (float*)(ws + 138289152);            // 512 KiB
  char* dob = (char*)d_out;
  unsigned short* LTe = (unsigned short*)(dob);               // 64 MiB
  unsigned short* vT  = (unsigned short*)(dob + 67108864);    // 64 MiB

  k_cvt_bf16<<<dim3(16384), dim3(256), 0, stream>>>(x, xbf, 4194304);
  k_gk<<<dim3(128), dim3(256), 0, stream>>>(Wk, qg, GK);
  k_wl<<<dim3(1024), dim3(256), 0, stream>>>(Wx, GK, Wcat);
  k_wv<<<dim3(1024), dim3(256), 0, stream>>>(Wx, Wv, Wcat);
  k_bias2<<<dim3(4), dim3(256), 0, stream>>>(bx, bk, bv, Wv, qg, GK, bias);
  k_wo_t<<<dim3(1024), dim3(256), 0, stream>>>(Wo, WoT);
  // GEMM1: [L|v] = x @ Wcat^T + bias -> P2 (softmaxed) + LTe (exp, transposed) + vT
  k_mm<1><<<dim3(1024), dim3(512), 131072, stream>>>(xbf, Wcat, bias, nullptr, P2, LTe,
                                                     vT, 4);
  k_pass1<<<dim3(32, 32), dim3(256), 0, stream>>>(LTe, vT, zpart, dpart);
  k_zred<<<dim3(512), dim3(256), 0, stream>>>(zpart, dpart, zbuf);
  k_zwo<<<dim3(4096), dim3(256), 0, stream>>>(zbuf, WoT, zWoT);
  // GEMM2: out = P2 @ zWoT_b + bo (overwrites LTe/vT scratch in d_out)
  k_mm<0><<<dim3(512), dim3(512), 131072, stream>>>(P2, zWoT, bo, out, nullptr, nullptr,
                                                    nullptr, 2);
}

// Round 6
// 326.194 us; speedup vs baseline: 1.0955x; 1.0955x over previous
//
#include <hip/hip_runtime.h>
#include <stdint.h>

#define DEV __device__ __forceinline__

typedef __attribute__((ext_vector_type(8))) short bf16x8;
typedef __attribute__((ext_vector_type(4))) float f32x4;
typedef __attribute__((ext_vector_type(8))) unsigned short u16x8;
typedef __attribute__((ext_vector_type(4))) unsigned short u16x4;

DEV unsigned short f2bf(float f) {
  union { float f; unsigned int u; } v; v.f = f;
  unsigned int u = v.u;
  return (unsigned short)((u + 0x7FFFu + ((u >> 16) & 1u)) >> 16);
}
DEV float bf2f(unsigned short u) {
  union { unsigned int u; float f; } v; v.u = ((unsigned int)u) << 16;
  return v.f;
}
DEV f32x4 mfma16(bf16x8 a, bf16x8 b, f32x4 c) {
  return __builtin_amdgcn_mfma_f32_16x16x32_bf16(a, b, c, 0, 0, 0);
}

// ---------------- convert x (fp32 -> bf16) ----------------
__global__ __launch_bounds__(256) void k_cvt_bf16(const float* __restrict__ in,
                                                  unsigned short* __restrict__ out,
                                                  int n8) {
  int i = blockIdx.x * 256 + threadIdx.x;
  if (i >= n8) return;
  const float4* p = (const float4*)in + (size_t)i * 2;
  float4 a = p[0], b = p[1];
  u16x8 o;
  o[0] = f2bf(a.x); o[1] = f2bf(a.y); o[2] = f2bf(a.z); o[3] = f2bf(a.w);
  o[4] = f2bf(b.x); o[5] = f2bf(b.y); o[6] = f2bf(b.z); o[7] = f2bf(b.w);
  ((u16x8*)out)[i] = o;
}

// ---------------- GK[h][s][dd] = sum_d Wk[dd][d] * G[h,s,d] ----------------
__global__ void k_gk(const float* __restrict__ Wk, const float* __restrict__ qg,
                     float* __restrict__ GK) {
  int idx = blockIdx.x * 256 + threadIdx.x;  // 32768
  int dd = idx & 63, hs = idx >> 6;
  float a = 0.f;
#pragma unroll 8
  for (int d = 0; d < 64; ++d) a += Wk[dd * 64 + d] * qg[(size_t)hs * 64 + d];
  GK[idx] = a;
}

// ---------------- Wcat rows 0..511: Wl^T[hs][c] ----------------
__global__ void k_wl(const float* __restrict__ Wx, const float* __restrict__ GK,
                     unsigned short* __restrict__ Wcat) {
  int idx = blockIdx.x * 256 + threadIdx.x;  // 262144
  int c = idx & 511, hs = idx >> 9;
  int h = hs >> 6;
  float a = 0.f;
#pragma unroll 8
  for (int dd = 0; dd < 64; ++dd) a += Wx[(size_t)c * 512 + h * 64 + dd] * GK[hs * 64 + dd];
  Wcat[(size_t)hs * 512 + c] = f2bf(a);
}

// ---------------- Wcat rows 512..1023: Wv^T fused ----------------
__global__ void k_wv(const float* __restrict__ Wx, const float* __restrict__ Wv,
                     unsigned short* __restrict__ Wcat) {
  int idx = blockIdx.x * 256 + threadIdx.x;  // 262144
  int c = idx & 511, o = idx >> 9;
  int h = o >> 6, dp = o & 63;
  float a = 0.f;
#pragma unroll 8
  for (int dd = 0; dd < 64; ++dd) a += Wx[(size_t)c * 512 + h * 64 + dd] * Wv[dd * 64 + dp];
  Wcat[(size_t)(512 + o) * 512 + c] = f2bf(a);
}

// ---------------- fused biases via GK ----------------
__global__ void k_bias2(const float* __restrict__ bx, const float* __restrict__ bk,
                        const float* __restrict__ bv, const float* __restrict__ Wv,
                        const float* __restrict__ qg, const float* __restrict__ GK,
                        float* __restrict__ bias) {
  int o = blockIdx.x * 256 + threadIdx.x;
  if (o >= 1024) return;
  if (o < 512) {
    int h = o >> 6;
    float a = 0.f;
    for (int dd = 0; dd < 64; ++dd) a += bx[h * 64 + dd] * GK[(size_t)o * 64 + dd];
    for (int dp = 0; dp < 64; ++dp) a += bk[dp] * qg[(size_t)o * 64 + dp];
    bias[o] = a;
  } else {
    int o2 = o - 512, h = o2 >> 6, dp = o2 & 63;
    float a = bv[dp];
    for (int dd = 0; dd < 64; ++dd) a += bx[h * 64 + dd] * Wv[dd * 64 + dp];
    bias[o] = a;
  }
}

__global__ void k_wo_t(const float* __restrict__ Wo, unsigned short* __restrict__ WoT) {
  int idx = blockIdx.x * 256 + threadIdx.x;  // 262144
  int i = idx >> 9, o = idx & 511;
  WoT[(size_t)o * 512 + i] = f2bf(Wo[(size_t)i * 512 + o]);
}

// =================== barrier-free streaming GEMM, 256x128 tile ===================
// 8 waves, each 32 rows x 128 cols. A: 32 coalesced 16B loads/thread into
// registers upfront (af[16][2], no LDS, no barriers). B: 128x512 bf16 = 128 KB
// preloaded ONCE to LDS (reg-staged, XOR swizzle bits 6-8 -> 2-way free).
// K-loop has ZERO barriers: waves free-run, SIMD hides each other's stalls.
// MODE 1 (fused GEMM1+pass1): per (mtile,head) block: E=exp(L-8), V; write
//   P2 (normalized E) + z_part = E^T@V (in-block MFMA) + den partials.
// MODE 0 (GEMM2): out = P2 @ zWoT_b^T + bo.
template <int MODE>
__global__ __launch_bounds__(512, 1) void k_mm2(const unsigned short* __restrict__ A,
                                                const unsigned short* __restrict__ Bsrc,
                                                const float* __restrict__ bias,
                                                unsigned short* __restrict__ P2,
                                                float* __restrict__ zpart,
                                                float* __restrict__ dpart,
                                                float* __restrict__ out) {
  extern __shared__ char lds[];  // 131072
  const int tid = threadIdx.x, w = tid >> 6, lane = tid & 63, l = lane & 15, g = lane >> 4;
  unsigned bid = blockIdx.x;
  int mtile, h, ntile;
  if (MODE == 1) {  // 2048 blocks; all 8 heads of an mtile on one XCD (bid&7 == mtile&7)
    int a = bid >> 3, c = bid & 7;
    mtile = (a & ~7) | c;
    h = a & 7;
    ntile = 0;
  } else {  // 1024 blocks; 4 ntiles of an mtile on one XCD
    mtile = ((bid >> 5) << 3) | (bid & 7);
    ntile = (bid >> 3) & 3;
    h = 0;
  }
  const int bm = mtile * 256;
  const int b = bm >> 14;

  // ---- A fragments upfront (32 x 16B coalesced loads, kept in VGPRs) ----
  const unsigned short* Arow = A + (size_t)(bm + w * 32) * 512;
  bf16x8 af[16][2];
#pragma unroll
  for (int ks = 0; ks < 16; ++ks)
#pragma unroll
    for (int fm = 0; fm < 2; ++fm)
      af[ks][fm] = *(const bf16x8*)(Arow + (size_t)(fm * 16 + l) * 512 + ks * 32 + g * 8);

  // ---- B preload: 128 rows x 512, swizzled write (both-sides XOR, bits 6-8) ----
  {
    int col = tid >> 2;
    const unsigned short* src;
    if (MODE == 1)
      src = Bsrc + (size_t)((col < 64) ? h * 64 + col : 512 + h * 64 + (col - 64)) * 512;
    else
      src = Bsrc + ((size_t)b * 512 + ntile * 128 + col) * 512;
#pragma unroll
    for (int j = 0; j < 16; ++j) {
      int chunk = (tid & 3) + j * 4;  // 16B chunk within row
      u16x8 vv = *(const u16x8*)(src + chunk * 8);
      *(u16x8*)(lds + col * 1024 + ((chunk * 16) ^ ((col & 7) << 6))) = vv;
    }
  }
  __syncthreads();

  // ---- barrier-free K-loop ----
  f32x4 acc[2][8] = {};
#pragma unroll
  for (int ks = 0; ks < 16; ++ks) {
    bf16x8 bfr[8];
#pragma unroll
    for (int fn = 0; fn < 8; ++fn)
      bfr[fn] = *(const bf16x8*)(lds + (fn * 16 + l) * 1024 + ((ks * 64 + g * 16) ^ ((l & 7) << 6)));
#pragma unroll
    for (int fn = 0; fn < 8; ++fn)
#pragma unroll
      for (int fm = 0; fm < 2; ++fm)
        acc[fm][fn] = mfma16(af[ks][fm], bfr[fn], acc[fm][fn]);
  }

  if (MODE == 0) {
    int nc0 = ntile * 128;
#pragma unroll
    for (int fm = 0; fm < 2; ++fm)
#pragma unroll
      for (int fn = 0; fn < 8; ++fn) {
        int colg = nc0 + fn * 16 + l;
        float bb = bias[colg];
#pragma unroll
        for (int r = 0; r < 4; ++r) {
          int row = bm + w * 32 + fm * 16 + g * 4 + r;
          out[(size_t)row * 512 + colg] = acc[fm][fn][r] + bb;
        }
      }
    return;
  }

  // ================= MODE 1 epilogue: softmax + in-block z =================
  float be[4], bv4[4];
#pragma unroll
  for (int fn = 0; fn < 4; ++fn) be[fn] = bias[h * 64 + fn * 16 + l];
#pragma unroll
  for (int fn = 0; fn < 4; ++fn) bv4[fn] = bias[512 + h * 64 + fn * 16 + l];
#pragma unroll
  for (int fm = 0; fm < 2; ++fm) {
#pragma unroll
    for (int fn = 0; fn < 4; ++fn)
#pragma unroll
      for (int r = 0; r < 4; ++r)
        acc[fm][fn][r] = __expf(acc[fm][fn][r] + be[fn] - 8.0f);
#pragma unroll
    for (int fn = 4; fn < 8; ++fn)
#pragma unroll
      for (int r = 0; r < 4; ++r) acc[fm][fn][r] += bv4[fn - 4];
  }
  // token row-sums over the 64 s-cols (fn 0-3 x 16 lanes)
  f32x4 rs[2];
#pragma unroll
  for (int fm = 0; fm < 2; ++fm)
#pragma unroll
    for (int r = 0; r < 4; ++r) {
      float t = (acc[fm][0][r] + acc[fm][1][r]) + (acc[fm][2][r] + acc[fm][3][r]);
#pragma unroll
      for (int m = 1; m < 16; m <<= 1) t += __shfl_xor(t, m);
      rs[fm][r] = t;
    }
  __syncthreads();  // B-LDS dead; reuse for ET/VT/denp
  unsigned short* ET = (unsigned short*)lds;             // [64 s][264]
  unsigned short* VT = (unsigned short*)(lds + 33792);   // [64 d][264]
  float* denp = (float*)(lds + 67584);                   // [8][64]
  int nb = w * 32;
#pragma unroll
  for (int fm = 0; fm < 2; ++fm)
#pragma unroll
    for (int fn = 0; fn < 4; ++fn)
#pragma unroll
      for (int r = 0; r < 4; ++r) {
        int nn = nb + fm * 16 + g * 4 + r;
        ET[(fn * 16 + l) * 264 + nn] = f2bf(acc[fm][fn][r]);
        VT[(fn * 16 + l) * 264 + nn] = f2bf(acc[fm][fn + 4][r]);
      }
#pragma unroll
  for (int fn = 0; fn < 4; ++fn) {
    float t = 0.f;
#pragma unroll
    for (int fm = 0; fm < 2; ++fm)
#pragma unroll
      for (int r = 0; r < 4; ++r) t += acc[fm][fn][r];
    t += __shfl_xor(t, 16);
    t += __shfl_xor(t, 32);
    if (g == 0) denp[w * 64 + fn * 16 + l] = t;
  }
  // P2 stores (normalized), overlapped with LDS settling
#pragma unroll
  for (int fm = 0; fm < 2; ++fm)
#pragma unroll
    for (int r = 0; r < 4; ++r) {
      float rinv = 1.f / rs[fm][r];
      int nglob = bm + nb + fm * 16 + g * 4 + r;
#pragma unroll
      for (int fn = 0; fn < 4; ++fn)
        P2[(size_t)nglob * 512 + h * 64 + fn * 16 + l] = f2bf(acc[fm][fn][r] * rinv);
    }
  __syncthreads();
  size_t mh = (size_t)mtile * 8 + h;
  if (w < 4) {  // z_part[s][d] = E^T @ V over this block's 256 tokens
    int s0 = w * 16;
    f32x4 za[4] = {};
#pragma unroll
    for (int ks2 = 0; ks2 < 8; ++ks2) {
      bf16x8 a2 = *(const bf16x8*)&ET[(s0 + l) * 264 + ks2 * 32 + g * 8];
#pragma unroll
      for (int fd = 0; fd < 4; ++fd) {
        bf16x8 b2 = *(const bf16x8*)&VT[(fd * 16 + l) * 264 + ks2 * 32 + g * 8];
        za[fd] = mfma16(a2, b2, za[fd]);
      }
    }
#pragma unroll
    for (int fd = 0; fd < 4; ++fd)
#pragma unroll
      for (int r = 0; r < 4; ++r)
        zpart[mh * 4096 + (s0 + g * 4 + r) * 64 + fd * 16 + l] = za[fd][r];
  } else if (w == 4) {  // den[s] = sum of wave partials
    int s = lane;
    float t = 0.f;
#pragma unroll
    for (int ww = 0; ww < 8; ++ww) t += denp[ww * 64 + s];
    dpart[mh * 64 + s] = t;
  }
}

// ---------------- reduce partials -> z fp32 [bh][s][d] ----------------
__global__ void k_zred(const float* __restrict__ zpart, const float* __restrict__ dpart,
                       float* __restrict__ z) {
  int idx = blockIdx.x * 256 + threadIdx.x;  // 131072
  int bh = idx >> 12, s = (idx >> 6) & 63, d = idx & 63;
  int b = bh >> 3, h = bh & 7;
  float num = 0.f, den = 0.f;
  for (int mm = 0; mm < 64; ++mm) {
    size_t mh = ((size_t)(b * 64 + mm)) * 8 + h;
    num += zpart[mh * 4096 + s * 64 + d];
    den += dpart[mh * 64 + s];
  }
  z[idx] = num / den;
}

// ---------------- zWoT[b][c][hs] = sum_d z[b,h,s,d] * WoT[c][h*64+d] ----------------
__global__ void k_zwo(const float* __restrict__ z, const unsigned short* __restrict__ WoT,
                      unsigned short* __restrict__ zWoT) {
  int idx = blockIdx.x * 256 + threadIdx.x;  // 1048576
  int hs = idx & 511, c = (idx >> 9) & 511, b = idx >> 18;
  int h = hs >> 6;
  const float* zp = z + ((size_t)(b * 8 + h) * 64 + (hs & 63)) * 64;
  const unsigned short* wp = WoT + (size_t)c * 512 + h * 64;
  float a = 0.f;
#pragma unroll 8
  for (int d = 0; d < 64; ++d) a += zp[d] * bf2f(wp[d]);
  zWoT[((size_t)(b * 512) + c) * 512 + hs] = f2bf(a);
}

extern "C" void kernel_launch(void* const* d_in, const int* in_sizes, int n_in,
                              void* d_out, int out_size, void* d_ws, size_t ws_size,
                              hipStream_t stream) {
  const float* x  = (const float*)d_in[0];
  const float* qg = (const float*)d_in[1];
  const float* Wx = (const float*)d_in[2];
  const float* bx = (const float*)d_in[3];
  const float* Wk = (const float*)d_in[4];
  const float* bk = (const float*)d_in[5];
  const float* Wv = (const float*)d_in[6];
  const float* bv = (const float*)d_in[7];
  const float* Wo = (const float*)d_in[8];
  const float* bo = (const float*)d_in[9];
  float* out = (float*)d_out;

  char* ws = (char*)d_ws;
  unsigned short* xbf  = (unsigned short*)(ws);               // 64 MiB
  unsigned short* P2   = (unsigned short*)(ws + 67108864);    // 64 MiB
  unsigned short* Wcat = (unsigned short*)(ws + 134217728);   // 1 MiB
  unsigned short* WoT  = (unsigned short*)(ws + 135266304);   // 0.5 MiB
  float* bias          = (float*)(ws + 135790592);            // 4 KiB
  float* GK            = (float*)(ws + 135794688);            // 128 KiB
  unsigned short* zWoT = (unsigned short*)(ws + 135925760);   // 2 MiB
  float* zbuf          = (float*)(ws + 138027008);            // 512 KiB
  // d_out doubles as scratch (fully dead before GEMM2 writes it):
  char* dob = (char*)d_out;
  float* zpart = (float*)(dob);                               // 32 MiB
  float* dpart = (float*)(dob + 33554432);                    // 512 KiB

  k_cvt_bf16<<<dim3(16384), dim3(256), 0, stream>>>(x, xbf, 4194304);
  k_gk<<<dim3(128), dim3(256), 0, stream>>>(Wk, qg, GK);
  k_wl<<<dim3(1024), dim3(256), 0, stream>>>(Wx, GK, Wcat);
  k_wv<<<dim3(1024), dim3(256), 0, stream>>>(Wx, Wv, Wcat);
  k_bias2<<<dim3(4), dim3(256), 0, stream>>>(bx, bk, bv, Wv, qg, GK, bias);
  k_wo_t<<<dim3(1024), dim3(256), 0, stream>>>(Wo, WoT);
  // fused GEMM1 + pass1: per (mtile, head) -> P2 + zpart + dpart
  k_mm2<1><<<dim3(2048), dim3(512), 131072, stream>>>(xbf, Wcat, bias, P2, zpart, dpart,
                                                      nullptr);
  k_zred<<<dim3(512), dim3(256), 0, stream>>>(zpart, dpart, zbuf);
  k_zwo<<<dim3(4096), dim3(256), 0, stream>>>(zbuf, WoT, zWoT);
  // GEMM2: out = P2 @ zWoT_b^T + bo
  k_mm2<0><<<dim3(1024), dim3(512), 131072, stream>>>(P2, zWoT, bo, nullptr, nullptr,
                                                      nullptr, out);
}

// Round 7
// 284.107 us; speedup vs baseline: 1.2577x; 1.1481x over previous
//
#include <hip/hip_runtime.h>
#include <stdint.h>

#define DEV __device__ __forceinline__

typedef __attribute__((ext_vector_type(8))) short bf16x8;
typedef __attribute__((ext_vector_type(4))) float f32x4;
typedef __attribute__((ext_vector_type(8))) unsigned short u16x8;

DEV unsigned short f2bf(float f) {
  union { float f; unsigned int u; } v; v.f = f;
  unsigned int u = v.u;
  return (unsigned short)((u + 0x7FFFu + ((u >> 16) & 1u)) >> 16);
}
DEV float bf2f(unsigned short u) {
  union { unsigned int u; float f; } v; v.u = ((unsigned int)u) << 16;
  return v.f;
}
DEV f32x4 mfma16(bf16x8 a, bf16x8 b, f32x4 c) {
  return __builtin_amdgcn_mfma_f32_16x16x32_bf16(a, b, c, 0, 0, 0);
}
DEV void gl_lds16(const void* g, void* l) {
  __builtin_amdgcn_global_load_lds(
      (const __attribute__((address_space(1))) void*)g,
      (__attribute__((address_space(3))) void*)l, 16, 0, 0);
}

// ---------------- convert x (fp32 -> bf16) ----------------
__global__ __launch_bounds__(256) void k_cvt_bf16(const float* __restrict__ in,
                                                  unsigned short* __restrict__ out,
                                                  int n8) {
  int i = blockIdx.x * 256 + threadIdx.x;
  if (i >= n8) return;
  const float4* p = (const float4*)in + (size_t)i * 2;
  float4 a = p[0], b = p[1];
  u16x8 o;
  o[0] = f2bf(a.x); o[1] = f2bf(a.y); o[2] = f2bf(a.z); o[3] = f2bf(a.w);
  o[4] = f2bf(b.x); o[5] = f2bf(b.y); o[6] = f2bf(b.z); o[7] = f2bf(b.w);
  ((u16x8*)out)[i] = o;
}

// ---------------- GK[h][s][dd] = sum_d Wk[dd][d] * G[h,s,d] ----------------
__global__ void k_gk(const float* __restrict__ Wk, const float* __restrict__ qg,
                     float* __restrict__ GK) {
  int idx = blockIdx.x * 256 + threadIdx.x;  // 32768
  int dd = idx & 63, hs = idx >> 6;
  float a = 0.f;
#pragma unroll 8
  for (int d = 0; d < 64; ++d) a += Wk[dd * 64 + d] * qg[(size_t)hs * 64 + d];
  GK[idx] = a;
}

// ---- Wcat head-interleaved: row h*128+s (s<64) = Wl^T; row h*128+64+dp = Wv^T ----
__global__ void k_wl(const float* __restrict__ Wx, const float* __restrict__ GK,
                     unsigned short* __restrict__ Wcat) {
  int idx = blockIdx.x * 256 + threadIdx.x;  // 262144
  int c = idx & 511, hs = idx >> 9;
  int h = hs >> 6, s = hs & 63;
  float a = 0.f;
#pragma unroll 8
  for (int dd = 0; dd < 64; ++dd) a += Wx[(size_t)c * 512 + h * 64 + dd] * GK[hs * 64 + dd];
  Wcat[(size_t)(h * 128 + s) * 512 + c] = f2bf(a);
}

__global__ void k_wv(const float* __restrict__ Wx, const float* __restrict__ Wv,
                     unsigned short* __restrict__ Wcat) {
  int idx = blockIdx.x * 256 + threadIdx.x;  // 262144
  int c = idx & 511, o = idx >> 9;
  int h = o >> 6, dp = o & 63;
  float a = 0.f;
#pragma unroll 8
  for (int dd = 0; dd < 64; ++dd) a += Wx[(size_t)c * 512 + h * 64 + dd] * Wv[dd * 64 + dp];
  Wcat[(size_t)(h * 128 + 64 + dp) * 512 + c] = f2bf(a);
}

// ---- bias head-interleaved: o = h*128+j; j<64 -> L-bias(h,s=j); else V-bias ----
__global__ void k_bias2(const float* __restrict__ bx, const float* __restrict__ bk,
                        const float* __restrict__ bv, const float* __restrict__ Wv,
                        const float* __restrict__ qg, const float* __restrict__ GK,
                        float* __restrict__ bias) {
  int o = blockIdx.x * 256 + threadIdx.x;
  if (o >= 1024) return;
  int h = o >> 7, j = o & 127;
  if (j < 64) {
    int hs = h * 64 + j;
    float a = 0.f;
    for (int dd = 0; dd < 64; ++dd) a += bx[h * 64 + dd] * GK[(size_t)hs * 64 + dd];
    for (int dp = 0; dp < 64; ++dp) a += bk[dp] * qg[(size_t)hs * 64 + dp];
    bias[o] = a;
  } else {
    int dp = j - 64;
    float a = bv[dp];
    for (int dd = 0; dd < 64; ++dd) a += bx[h * 64 + dd] * Wv[dd * 64 + dp];
    bias[o] = a;
  }
}

__global__ void k_wo_t(const float* __restrict__ Wo, unsigned short* __restrict__ WoT) {
  int idx = blockIdx.x * 256 + threadIdx.x;  // 262144
  int i = idx >> 9, o = idx & 511;
  WoT[(size_t)o * 512 + i] = f2bf(Wo[(size_t)i * 512 + o]);
}

// =================== 128x128 GEMM, 4 waves, swizzled LDS, 4 blocks/CU ===================
// m97/R1 skeleton: per K-tile {global_load_lds stage -> sync -> 32 MFMA -> sync},
// cross-block overlap hides the barrier drain (needs >=4 blocks/CU).
// T2 swizzle: source pre-swizzled (cb ^ (row&7)<<4), ds_read XORs the same key.
// MODE 1 (GEMM1, ntile=head h): cols j<64 = E-cols (exp+rowsum+P2), j>=64 = V-cols;
//   epilogue computes z_part = E^T@V in-block via LDS transpose. Deletes pass1.
// MODE 0 (GEMM2): out = P2 @ zWoT_b^T + bo (fp32).
template <int MODE>
__global__ __launch_bounds__(256, 4) void k_mm(const unsigned short* __restrict__ A,
                                               const unsigned short* __restrict__ BTg,
                                               const float* __restrict__ bias,
                                               unsigned short* __restrict__ P2,
                                               float* __restrict__ zpart,
                                               float* __restrict__ dpart,
                                               float* __restrict__ outF) {
  __shared__ __align__(16) char lds[35328];  // staging 32KB; epilogue ET/VT/denp 34.5KB
  const int tid = threadIdx.x;
  const int w = tid >> 6, lane = tid & 63, l = lane & 15, g = lane >> 4;
  unsigned bid = blockIdx.x;
  int mtile, ntile;
  if (MODE == 1) {  // 4096 blocks: XCD-chunked, 8 heads of one mtile adjacent
    unsigned nbid = (bid & 7) * 512 + (bid >> 3);
    mtile = nbid >> 3;
    ntile = nbid & 7;
  } else {  // 2048 blocks
    unsigned nbid = (bid & 7) * 256 + (bid >> 3);
    mtile = nbid >> 2;
    ntile = nbid & 3;
  }
  const int bm = mtile * 128;
  const int bn = ntile * 128;
  const int b = mtile >> 7;  // batch (128 mtiles per batch)
  const unsigned short* BT = (MODE == 0) ? BTg + ((size_t)b << 18) : BTg;
  const int wm = (w >> 1) * 64, wn = (w & 1) * 64;
  char* As = lds;
  char* Bs = lds + 16384;
  f32x4 acc[4][4] = {};
  const int sw = (l & 7) << 4;

  for (int t = 0; t < 8; ++t) {
#pragma unroll
    for (int i = 0; i < 4; ++i) {  // stage 16KB each of A,B (coalesced, pre-swizzled src)
      int off = i * 4096 + tid * 16;
      int row = off >> 7;
      int cb = (off & 127) ^ ((row & 7) << 4);
      gl_lds16(A + (size_t)(bm + row) * 512 + t * 64 + (cb >> 1), As + off);
      gl_lds16(BT + (size_t)(bn + row) * 512 + t * 64 + (cb >> 1), Bs + off);
    }
    __syncthreads();
#pragma unroll
    for (int ks = 0; ks < 2; ++ks) {
      int kb = (ks * 64 + g * 16) ^ sw;
      bf16x8 af[4], bf[4];
#pragma unroll
      for (int fm = 0; fm < 4; ++fm)
        af[fm] = *(const bf16x8*)(As + (wm + fm * 16 + l) * 128 + kb);
#pragma unroll
      for (int fn = 0; fn < 4; ++fn)
        bf[fn] = *(const bf16x8*)(Bs + (wn + fn * 16 + l) * 128 + kb);
#pragma unroll
      for (int fm = 0; fm < 4; ++fm)
#pragma unroll
        for (int fn = 0; fn < 4; ++fn)
          acc[fm][fn] = mfma16(af[fm], bf[fn], acc[fm][fn]);
    }
    __syncthreads();
  }

  if (MODE == 0) {
#pragma unroll
    for (int fm = 0; fm < 4; ++fm)
#pragma unroll
      for (int fn = 0; fn < 4; ++fn) {
        int col = bn + wn + fn * 16 + l;
        float bb = bias[col];
#pragma unroll
        for (int r = 0; r < 4; ++r)
          outF[(size_t)(bm + wm + fm * 16 + g * 4 + r) * 512 + col] = acc[fm][fn][r] + bb;
      }
    return;
  }

  // ================= MODE 1 epilogue (LDS staging is dead) =================
  const int h = ntile;
  unsigned short* ET = (unsigned short*)lds;            // [64 s][136 n-pad]
  unsigned short* VT = (unsigned short*)(lds + 17408);  // [64 d][136 n-pad]
  float* denp = (float*)(lds + 34816);                  // [2][64]
  float bc[4];
#pragma unroll
  for (int fn = 0; fn < 4; ++fn) bc[fn] = bias[h * 128 + wn + fn * 16 + l];
  if (wn == 0) {  // E-waves (cols 0..63 = slots)
#pragma unroll
    for (int fm = 0; fm < 4; ++fm)
#pragma unroll
      for (int fn = 0; fn < 4; ++fn)
#pragma unroll
        for (int r = 0; r < 4; ++r)
          acc[fm][fn][r] = __expf(acc[fm][fn][r] + bc[fn] - 8.0f);
    // per-token rowsum over 64 slot-cols (within wave: fn x l)
#pragma unroll
    for (int fm = 0; fm < 4; ++fm) {
      f32x4 rs;
#pragma unroll
      for (int r = 0; r < 4; ++r) {
        float t2 = (acc[fm][0][r] + acc[fm][1][r]) + (acc[fm][2][r] + acc[fm][3][r]);
#pragma unroll
        for (int m = 1; m < 16; m <<= 1) t2 += __shfl_xor(t2, m);
        rs[r] = t2;
      }
#pragma unroll
      for (int r = 0; r < 4; ++r) {
        float rinv = 1.f / rs[r];
        int n = bm + wm + fm * 16 + g * 4 + r;
#pragma unroll
        for (int fn = 0; fn < 4; ++fn)
          P2[(size_t)n * 512 + h * 64 + fn * 16 + l] = f2bf(acc[fm][fn][r] * rinv);
      }
    }
    // E^T into LDS + per-slot colsum partials
#pragma unroll
    for (int fm = 0; fm < 4; ++fm)
#pragma unroll
      for (int fn = 0; fn < 4; ++fn)
#pragma unroll
        for (int r = 0; r < 4; ++r)
          ET[(fn * 16 + l) * 136 + wm + fm * 16 + g * 4 + r] = f2bf(acc[fm][fn][r]);
#pragma unroll
    for (int fn = 0; fn < 4; ++fn) {
      float t2 = 0.f;
#pragma unroll
      for (int fm = 0; fm < 4; ++fm)
#pragma unroll
        for (int r = 0; r < 4; ++r) t2 += acc[fm][fn][r];
      t2 += __shfl_xor(t2, 16);
      t2 += __shfl_xor(t2, 32);
      if (g == 0) denp[(w >> 1) * 64 + fn * 16 + l] = t2;
    }
  } else {  // V-waves (cols 64..127 = dims)
#pragma unroll
    for (int fm = 0; fm < 4; ++fm)
#pragma unroll
      for (int fn = 0; fn < 4; ++fn)
#pragma unroll
        for (int r = 0; r < 4; ++r)
          VT[(fn * 16 + l) * 136 + wm + fm * 16 + g * 4 + r] =
              f2bf(acc[fm][fn][r] + bc[fn]);
  }
  __syncthreads();
  // z_part[s][d] = E^T @ V over this tile's 128 tokens (all 4 waves, 16 s-rows each)
  f32x4 za[4] = {};
#pragma unroll
  for (int ks2 = 0; ks2 < 4; ++ks2) {
    bf16x8 a2 = *(const bf16x8*)&ET[(w * 16 + l) * 136 + ks2 * 32 + g * 8];
#pragma unroll
    for (int fd = 0; fd < 4; ++fd) {
      bf16x8 b2 = *(const bf16x8*)&VT[(fd * 16 + l) * 136 + ks2 * 32 + g * 8];
      za[fd] = mfma16(a2, b2, za[fd]);
    }
  }
  size_t mh = (size_t)mtile * 8 + h;
#pragma unroll
  for (int fd = 0; fd < 4; ++fd)
#pragma unroll
    for (int r = 0; r < 4; ++r)
      zpart[mh * 4096 + (w * 16 + g * 4 + r) * 64 + fd * 16 + l] = za[fd][r];
  if (w == 0) dpart[mh * 64 + lane] = denp[lane] + denp[64 + lane];
}

// ---------------- reduce partials -> z fp32 [bh][s][d] ----------------
__global__ void k_zred(const float* __restrict__ zpart, const float* __restrict__ dpart,
                       float* __restrict__ z) {
  int idx = blockIdx.x * 256 + threadIdx.x;  // 131072
  int bh = idx >> 12, s = (idx >> 6) & 63, d = idx & 63;
  int b = bh >> 3, h = bh & 7;
  float num = 0.f, den = 0.f;
  for (int mm = 0; mm < 128; ++mm) {
    size_t mh = ((size_t)(b * 128 + mm)) * 8 + h;
    num += zpart[mh * 4096 + s * 64 + d];
    den += dpart[mh * 64 + s];
  }
  z[idx] = num / den;
}

// ---------------- zWoT[b][c][hs] = sum_d z[b,h,s,d] * WoT[c][h*64+d] ----------------
__global__ void k_zwo(const float* __restrict__ z, const unsigned short* __restrict__ WoT,
                      unsigned short* __restrict__ zWoT) {
  int idx = blockIdx.x * 256 + threadIdx.x;  // 1048576
  int hs = idx & 511, c = (idx >> 9) & 511, b = idx >> 18;
  int h = hs >> 6;
  const float* zp = z + ((size_t)(b * 8 + h) * 64 + (hs & 63)) * 64;
  const unsigned short* wp = WoT + (size_t)c * 512 + h * 64;
  float a = 0.f;
#pragma unroll 8
  for (int d = 0; d < 64; ++d) a += zp[d] * bf2f(wp[d]);
  zWoT[((size_t)(b * 512) + c) * 512 + hs] = f2bf(a);
}

extern "C" void kernel_launch(void* const* d_in, const int* in_sizes, int n_in,
                              void* d_out, int out_size, void* d_ws, size_t ws_size,
                              hipStream_t stream) {
  const float* x  = (const float*)d_in[0];
  const float* qg = (const float*)d_in[1];
  const float* Wx = (const float*)d_in[2];
  const float* bx = (const float*)d_in[3];
  const float* Wk = (const float*)d_in[4];
  const float* bk = (const float*)d_in[5];
  const float* Wv = (const float*)d_in[6];
  const float* bv = (const float*)d_in[7];
  const float* Wo = (const float*)d_in[8];
  const float* bo = (const float*)d_in[9];
  float* out = (float*)d_out;

  char* ws = (char*)d_ws;
  unsigned short* xbf  = (unsigned short*)(ws);               // 64 MiB
  unsigned short* P2   = (unsigned short*)(ws + 67108864);    // 64 MiB
  unsigned short* Wcat = (unsigned short*)(ws + 134217728);   // 1 MiB
  unsigned short* WoT  = (unsigned short*)(ws + 135266304);   // 0.5 MiB
  float* bias          = (float*)(ws + 135790592);            // 4 KiB
  float* GK            = (float*)(ws + 135794688);            // 128 KiB
  unsigned short* zWoT = (unsigned short*)(ws + 135925760);   // 2 MiB
  float* zbuf          = (float*)(ws + 138027008);            // 512 KiB
  // d_out doubles as scratch (dead before GEMM2 writes it):
  char* dob = (char*)d_out;
  float* zpart = (float*)(dob);                               // 64 MiB (4096 x 4096 f32)
  float* dpart = (float*)(dob + 67108864);                    // 1 MiB

  k_cvt_bf16<<<dim3(16384), dim3(256), 0, stream>>>(x, xbf, 4194304);
  k_gk<<<dim3(128), dim3(256), 0, stream>>>(Wk, qg, GK);
  k_wl<<<dim3(1024), dim3(256), 0, stream>>>(Wx, GK, Wcat);
  k_wv<<<dim3(1024), dim3(256), 0, stream>>>(Wx, Wv, Wcat);
  k_bias2<<<dim3(4), dim3(256), 0, stream>>>(bx, bk, bv, Wv, qg, GK, bias);
  k_wo_t<<<dim3(1024), dim3(256), 0, stream>>>(Wo, WoT);
  // GEMM1 + fused z: per (mtile, head) -> P2, zpart, dpart
  k_mm<1><<<dim3(4096), dim3(256), 0, stream>>>(xbf, Wcat, bias, P2, zpart, dpart, nullptr);
  k_zred<<<dim3(512), dim3(256), 0, stream>>>(zpart, dpart, zbuf);
  k_zwo<<<dim3(4096), dim3(256), 0, stream>>>(zbuf, WoT, zWoT);
  // GEMM2: out = P2 @ zWoT_b^T + bo
  k_mm<0><<<dim3(2048), dim3(256), 0, stream>>>(P2, zWoT, bo, nullptr, nullptr, nullptr, out);
}